// Round 1
// baseline (1020.266 us; speedup 1.0000x reference)
//
#include <hip/hip_runtime.h>

// Problem constants
#define NWIN 2048   // 2 * 32 * 32 windows
#define DIM 256
#define HEADS 8
#define HD 32
#define WA 64       // window area
#define N1 128      // query count
#define SCALE 0.17677669529663687f  // 32^-0.5

typedef _Float16 hvec8 __attribute__((ext_vector_type(8)));
typedef _Float16 hvec4 __attribute__((ext_vector_type(4)));
typedef float fvec4 __attribute__((ext_vector_type(4)));

union H8 { hvec8 v8; hvec4 v4[2]; };

// ---------------------------------------------------------------------------
// Prep: convert q (scaled), kv_w, proj_w to f16; materialize rel-pos bias fp32.
// ---------------------------------------------------------------------------
__global__ void prep_kernel(const float* __restrict__ embeds,
                            const float* __restrict__ rpb,
                            const float* __restrict__ kvw,
                            const float* __restrict__ pjw,
                            _Float16* __restrict__ qh,
                            _Float16* __restrict__ kvwh,
                            _Float16* __restrict__ pjwh,
                            float* __restrict__ biasf) {
  int t = blockIdx.x * 256 + threadIdx.x;  // 0..131071
  kvwh[t] = (_Float16)kvw[t];              // [512][256] same layout
  if (t < 65536) pjwh[t] = (_Float16)pjw[t];  // [256][256]
  if (t < 32768) {
    // q: [h][n1][d] <- embeds[n1*256 + h*32 + d] * SCALE
    int h = t >> 12, n1 = (t >> 5) & 127, d = t & 31;
    qh[t] = (_Float16)(embeds[n1 * 256 + h * 32 + d] * SCALE);
    // bias: [h][p][kk] fp32, p,kk in [0,64)
    int p = (t >> 6) & 63, kk = t & 63;
    int ridx = ((p >> 3) - (kk >> 3) + 7) * 15 + ((p & 7) - (kk & 7) + 7);
    biasf[t] = rpb[ridx * 8 + h];
  }
}

// ---------------------------------------------------------------------------
// Fused: window KV-proj -> 8-head attention -> out proj. One block per window.
// 512 threads = 8 waves. Wave w: stage A kv-channel slice, stage B head w,
// stage C out-channel slice.
// ---------------------------------------------------------------------------
__global__ __launch_bounds__(512, 2) void attn_kernel(
    const float* __restrict__ x,
    const float* __restrict__ kvb,
    const float* __restrict__ pjb,
    const _Float16* __restrict__ qh,
    const _Float16* __restrict__ kvwh,
    const _Float16* __restrict__ pjwh,
    const float* __restrict__ biasf,
    float* __restrict__ out) {

  __shared__ _Float16 Ks[64 * 256];    // K natural [kk][chan]      32 KB
  __shared__ _Float16 Vt[256 * 68];    // V transposed [chan][kk]   34 KB (pitch 68: conflict-free)
  __shared__ _Float16 Pc[8][16 * 68];  // per-wave P chunk [q16][kk] 17 KB
  __shared__ _Float16 Os[128 * 264];   // attn out [q][chan]        66 KB (pitch 264: 16B-aligned rows, 2-way max)

  const int tid = threadIdx.x;
  const int wv = tid >> 6;
  const int lane = tid & 63;
  const int l15 = lane & 15;
  const int l4 = lane >> 4;

  const int w = blockIdx.x;
  const int b = w >> 10, hb = (w >> 5) & 31, wb = w & 31;

  const fvec4 fz = {0.f, 0.f, 0.f, 0.f};

  // ================= Stage A: kv[64][512] = X[64][256] @ kv_w^T + kv_b ======
  // wave wv covers kv channels [wv*64, wv*64+64): waves 0-3 -> K, 4-7 -> V
  const int n0w = wv * 64;
  const float* xr[4];
#pragma unroll
  for (int mt = 0; mt < 4; ++mt) {
    int m = mt * 16 + l15;            // window row (A-operand row)
    int i = m >> 3, j = m & 7;
    xr[mt] = x + ((((size_t)b * 256 + hb * 8 + i) * 256 + wb * 8 + j) << 8);
  }
  fvec4 acc[4][4];
#pragma unroll
  for (int mt = 0; mt < 4; ++mt)
#pragma unroll
    for (int nt = 0; nt < 4; ++nt) acc[mt][nt] = fz;

  for (int ks = 0; ks < 8; ++ks) {
    const int k0 = ks * 32 + l4 * 8;  // A/B operand k-range: 8 consecutive
    hvec8 af[4];
#pragma unroll
    for (int mt = 0; mt < 4; ++mt) {
      fvec4 u0 = *(const fvec4*)(xr[mt] + k0);
      fvec4 u1 = *(const fvec4*)(xr[mt] + k0 + 4);
      hvec8 a;
      a[0] = (_Float16)u0[0]; a[1] = (_Float16)u0[1];
      a[2] = (_Float16)u0[2]; a[3] = (_Float16)u0[3];
      a[4] = (_Float16)u1[0]; a[5] = (_Float16)u1[1];
      a[6] = (_Float16)u1[2]; a[7] = (_Float16)u1[3];
      af[mt] = a;
    }
    hvec8 bfg[4];
#pragma unroll
    for (int nt = 0; nt < 4; ++nt)
      bfg[nt] = *(const hvec8*)(kvwh + (size_t)(n0w + nt * 16 + l15) * 256 + k0);
#pragma unroll
    for (int mt = 0; mt < 4; ++mt)
#pragma unroll
      for (int nt = 0; nt < 4; ++nt)
        acc[mt][nt] = __builtin_amdgcn_mfma_f32_16x16x32_f16(af[mt], bfg[nt], acc[mt][nt], 0, 0, 0);
  }
  // epilogue: + kv_b, write K natural / V transposed to LDS (f16)
#pragma unroll
  for (int nt = 0; nt < 4; ++nt) {
    const int n = n0w + nt * 16 + l15;     // kv channel (D col)
    const float bias = kvb[n];
    if (wv < 4) {
#pragma unroll
      for (int mt = 0; mt < 4; ++mt)
#pragma unroll
        for (int r = 0; r < 4; ++r) {
          int m = mt * 16 + l4 * 4 + r;    // window row (D row)
          Ks[m * 256 + n] = (_Float16)(acc[mt][nt][r] + bias);
        }
    } else {
      const int vn = n - 256;              // v channel 0..255
#pragma unroll
      for (int mt = 0; mt < 4; ++mt)
#pragma unroll
        for (int r = 0; r < 4; ++r) {
          int m = mt * 16 + l4 * 4 + r;
          Vt[vn * 68 + m] = (_Float16)(acc[mt][nt][r] + bias);
        }
    }
  }
  __syncthreads();

  // ================= Stage B: attention, head h = wv =========================
  {
    const int h = wv;
    // K B-frags: B[k=d][n=kk] = Ks[kk][h*32+d]; 4 N-tiles, one frag covers K=32
    hvec8 kf[4];
#pragma unroll
    for (int nt = 0; nt < 4; ++nt)
      kf[nt] = *(const hvec8*)&Ks[(nt * 16 + l15) * 256 + h * 32 + l4 * 8];
    // V B-frags: B[k=kk][n=d] = Vt[h*32+d][kk]; 2 N-tiles x 2 K-steps
    H8 vf[2][2];
#pragma unroll
    for (int nv = 0; nv < 2; ++nv)
#pragma unroll
      for (int k2 = 0; k2 < 2; ++k2) {
        int row = h * 32 + nv * 16 + l15;
        int kkb = k2 * 32 + l4 * 8;
        vf[nv][k2].v4[0] = *(const hvec4*)&Vt[row * 68 + kkb];
        vf[nv][k2].v4[1] = *(const hvec4*)&Vt[row * 68 + kkb + 4];
      }
    // Q A-frags for 8 M-tiles (global, L2-hot)
    hvec8 qf[8];
#pragma unroll
    for (int mt = 0; mt < 8; ++mt)
      qf[mt] = *(const hvec8*)(qh + (size_t)(h * 128 + mt * 16 + l15) * 32 + l4 * 8);

    const float* bh = biasf + h * 4096;
    _Float16* pc = Pc[wv];

    for (int mt = 0; mt < 8; ++mt) {
      fvec4 s[4];
#pragma unroll
      for (int nt = 0; nt < 4; ++nt)
        s[nt] = __builtin_amdgcn_mfma_f32_16x16x32_f16(qf[mt], kf[nt], fz, 0, 0, 0);
      // + relative position bias (rows tile mod 64)
      const int pbase = (mt * 16 + l4 * 4) & 63;
#pragma unroll
      for (int r = 0; r < 4; ++r)
#pragma unroll
        for (int nt = 0; nt < 4; ++nt)
          s[nt][r] += bh[(pbase + r) * 64 + nt * 16 + l15];
      // in-register softmax over kk (4 in-lane regs x 16 lanes)
#pragma unroll
      for (int r = 0; r < 4; ++r) {
        float mx = fmaxf(fmaxf(s[0][r], s[1][r]), fmaxf(s[2][r], s[3][r]));
        mx = fmaxf(mx, __shfl_xor(mx, 1));
        mx = fmaxf(mx, __shfl_xor(mx, 2));
        mx = fmaxf(mx, __shfl_xor(mx, 4));
        mx = fmaxf(mx, __shfl_xor(mx, 8));
        float sm = 0.f;
#pragma unroll
        for (int nt = 0; nt < 4; ++nt) {
          float e = __expf(s[nt][r] - mx);
          s[nt][r] = e;
          sm += e;
        }
        sm += __shfl_xor(sm, 1);
        sm += __shfl_xor(sm, 2);
        sm += __shfl_xor(sm, 4);
        sm += __shfl_xor(sm, 8);
        const float iv = 1.0f / sm;
#pragma unroll
        for (int nt = 0; nt < 4; ++nt) s[nt][r] *= iv;
      }
      // P chunk -> LDS (wave-private; DS ops in-order within a wave)
#pragma unroll
      for (int nt = 0; nt < 4; ++nt)
#pragma unroll
        for (int r = 0; r < 4; ++r)
          pc[(l4 * 4 + r) * 68 + nt * 16 + l15] = (_Float16)s[nt][r];
      // P A-frags: A[m=q][k=kk]
      H8 pf[2];
#pragma unroll
      for (int k2 = 0; k2 < 2; ++k2) {
        int kkb = k2 * 32 + l4 * 8;
        pf[k2].v4[0] = *(const hvec4*)&pc[l15 * 68 + kkb];
        pf[k2].v4[1] = *(const hvec4*)&pc[l15 * 68 + kkb + 4];
      }
      fvec4 o[2];
#pragma unroll
      for (int nv = 0; nv < 2; ++nv) {
        o[nv] = __builtin_amdgcn_mfma_f32_16x16x32_f16(pf[0].v8, vf[nv][0].v8, fz, 0, 0, 0);
        o[nv] = __builtin_amdgcn_mfma_f32_16x16x32_f16(pf[1].v8, vf[nv][1].v8, o[nv], 0, 0, 0);
      }
#pragma unroll
      for (int nv = 0; nv < 2; ++nv)
#pragma unroll
        for (int r = 0; r < 4; ++r) {
          int row = mt * 16 + l4 * 4 + r;
          int col = h * 32 + nv * 16 + l15;
          Os[row * 264 + col] = (_Float16)o[nv][r];
        }
    }
  }
  __syncthreads();

  // ================= Stage C: out = Os[128][256] @ proj_w^T + proj_b ========
  {
    const int c0 = wv * 32;  // out-channel slice per wave
    fvec4 po[8][2];
#pragma unroll
    for (int mt = 0; mt < 8; ++mt)
#pragma unroll
      for (int nb = 0; nb < 2; ++nb) po[mt][nb] = fz;

    for (int ks = 0; ks < 8; ++ks) {
      const int k0 = ks * 32 + l4 * 8;
      hvec8 am[8];
#pragma unroll
      for (int mt = 0; mt < 8; ++mt)
        am[mt] = *(const hvec8*)&Os[(mt * 16 + l15) * 264 + k0];
      hvec8 bn[2];
#pragma unroll
      for (int nb = 0; nb < 2; ++nb)
        bn[nb] = *(const hvec8*)(pjwh + (size_t)(c0 + nb * 16 + l15) * 256 + k0);
#pragma unroll
      for (int mt = 0; mt < 8; ++mt)
#pragma unroll
        for (int nb = 0; nb < 2; ++nb)
          po[mt][nb] = __builtin_amdgcn_mfma_f32_16x16x32_f16(am[mt], bn[nb], po[mt][nb], 0, 0, 0);
    }
    float pb[2];
#pragma unroll
    for (int nb = 0; nb < 2; ++nb) pb[nb] = pjb[c0 + nb * 16 + l15];
    float* ow = out + (size_t)w * (N1 * DIM);
#pragma unroll
    for (int mt = 0; mt < 8; ++mt)
#pragma unroll
      for (int nb = 0; nb < 2; ++nb)
#pragma unroll
        for (int r = 0; r < 4; ++r) {
          int row = mt * 16 + l4 * 4 + r;
          int col = c0 + nb * 16 + l15;
          ow[row * 256 + col] = po[mt][nb][r] + pb[nb];
        }
  }
}

// ---------------------------------------------------------------------------
extern "C" void kernel_launch(void* const* d_in, const int* in_sizes, int n_in,
                              void* d_out, int out_size, void* d_ws, size_t ws_size,
                              hipStream_t stream) {
  (void)in_sizes; (void)n_in; (void)out_size; (void)ws_size;
  const float* embeds = (const float*)d_in[0];  // [1,128,256]
  const float* x      = (const float*)d_in[1];  // [2,256,256,256]
  const float* rpb    = (const float*)d_in[2];  // [225,8]
  const float* kvw    = (const float*)d_in[3];  // [512,256]
  const float* kvb    = (const float*)d_in[4];  // [512]
  const float* pjw    = (const float*)d_in[5];  // [256,256]
  const float* pjb    = (const float*)d_in[6];  // [256]
  float* out = (float*)d_out;                   // [2048,128,256]

  char* ws = (char*)d_ws;                       // 576 KB used
  _Float16* qh    = (_Float16*)(ws);            // 65536 B  : q f16 [8][128][32]
  _Float16* kvwh  = (_Float16*)(ws + 65536);    // 262144 B : kv_w f16
  _Float16* pjwh  = (_Float16*)(ws + 327680);   // 131072 B : proj_w f16
  float*    biasf = (float*)(ws + 458752);      // 131072 B : bias fp32 [8][64][64]

  prep_kernel<<<512, 256, 0, stream>>>(embeds, rpb, kvw, pjw, qh, kvwh, pjwh, biasf);
  attn_kernel<<<NWIN, 512, 0, stream>>>(x, kvb, pjb, qh, kvwh, pjwh, biasf, out);
}

// Round 2
// 801.306 us; speedup vs baseline: 1.2733x; 1.2733x over previous
//
#include <hip/hip_runtime.h>

// Problem constants
#define NWIN 2048   // 2 * 32 * 32 windows
#define DIM 256
#define HEADS 8
#define HD 32
#define WA 64       // window area
#define N1 128      // query count
#define SCALE 0.17677669529663687f  // 32^-0.5

typedef _Float16 hvec8 __attribute__((ext_vector_type(8)));
typedef _Float16 hvec4 __attribute__((ext_vector_type(4)));
typedef float fvec4 __attribute__((ext_vector_type(4)));

union H8 { hvec8 v8; hvec4 v4[2]; };

// ---------------------------------------------------------------------------
// Prep: convert q (scaled), kv_w, proj_w to f16; materialize rel-pos bias fp32.
// ---------------------------------------------------------------------------
__global__ void prep_kernel(const float* __restrict__ embeds,
                            const float* __restrict__ rpb,
                            const float* __restrict__ kvw,
                            const float* __restrict__ pjw,
                            _Float16* __restrict__ qh,
                            _Float16* __restrict__ kvwh,
                            _Float16* __restrict__ pjwh,
                            float* __restrict__ biasf) {
  int t = blockIdx.x * 256 + threadIdx.x;  // 0..131071
  kvwh[t] = (_Float16)kvw[t];              // [512][256] same layout
  if (t < 65536) pjwh[t] = (_Float16)pjw[t];  // [256][256]
  if (t < 32768) {
    // q: [h][n1][d] <- embeds[n1*256 + h*32 + d] * SCALE
    int h = t >> 12, n1 = (t >> 5) & 127, d = t & 31;
    qh[t] = (_Float16)(embeds[n1 * 256 + h * 32 + d] * SCALE);
    // bias: [h][p][kk] fp32, p,kk in [0,64)
    int p = (t >> 6) & 63, kk = t & 63;
    int ridx = ((p >> 3) - (kk >> 3) + 7) * 15 + ((p & 7) - (kk & 7) + 7);
    biasf[t] = rpb[ridx * 8 + h];
  }
}

// ---------------------------------------------------------------------------
// Fused: window KV-proj -> 8-head attention -> out proj. One block per window.
// 512 threads = 8 waves. LDS aliased across phases (67 KB total -> 2 blk/CU):
//   phase A : Ks[64][264] (33792 B) | Vt[256][68] (34816 B)
//   phase BC: Os[64][264] (33792 B) | Pc[8][16][68] (17408 B)
// Stage B/C run twice (M-halves, rows 0-63 then 64-127) so Os fits 64 rows.
// K/V/Q fragments live in registers across the whole half-loop.
// ---------------------------------------------------------------------------
__global__ __launch_bounds__(512, 4) void attn_kernel(
    const float* __restrict__ x,
    const float* __restrict__ kvb,
    const float* __restrict__ pjb,
    const _Float16* __restrict__ qh,
    const _Float16* __restrict__ kvwh,
    const _Float16* __restrict__ pjwh,
    const float* __restrict__ biasf,
    float* __restrict__ out) {

  __shared__ __align__(16) char smem[68608];
  _Float16* const Ks = (_Float16*)smem;            // [64][264] K natural
  _Float16* const Vt = (_Float16*)(smem + 33792);  // [256][68] V transposed
  _Float16* const Os = (_Float16*)smem;            // [64][264] attn out half
  _Float16* const Pc = (_Float16*)(smem + 33792);  // [8][16][68] per-wave P

  const int tid = threadIdx.x;
  const int wv = tid >> 6;
  const int lane = tid & 63;
  const int l15 = lane & 15;
  const int l4 = lane >> 4;

  const int w = blockIdx.x;
  const int b = w >> 10, hb = (w >> 5) & 31, wb = w & 31;

  const fvec4 fz = {0.f, 0.f, 0.f, 0.f};

  // ================= Stage A: kv[64][512] = X[64][256] @ kv_w^T + kv_b ======
  // wave wv covers kv channels [wv*64, wv*64+64): waves 0-3 -> K, 4-7 -> V
  {
    const int n0w = wv * 64;
    const float* xr[4];
#pragma unroll
    for (int mt = 0; mt < 4; ++mt) {
      int m = mt * 16 + l15;            // window row (A-operand row)
      int i = m >> 3, j = m & 7;
      xr[mt] = x + ((((size_t)b * 256 + hb * 8 + i) * 256 + wb * 8 + j) << 8);
    }
    fvec4 acc[4][4];
#pragma unroll
    for (int mt = 0; mt < 4; ++mt)
#pragma unroll
      for (int nt = 0; nt < 4; ++nt) acc[mt][nt] = fz;

    for (int ks = 0; ks < 8; ++ks) {
      const int k0 = ks * 32 + l4 * 8;  // A/B operand k-range: 8 consecutive
      hvec8 af[4];
#pragma unroll
      for (int mt = 0; mt < 4; ++mt) {
        fvec4 u0 = *(const fvec4*)(xr[mt] + k0);
        fvec4 u1 = *(const fvec4*)(xr[mt] + k0 + 4);
        hvec8 a;
        a[0] = (_Float16)u0[0]; a[1] = (_Float16)u0[1];
        a[2] = (_Float16)u0[2]; a[3] = (_Float16)u0[3];
        a[4] = (_Float16)u1[0]; a[5] = (_Float16)u1[1];
        a[6] = (_Float16)u1[2]; a[7] = (_Float16)u1[3];
        af[mt] = a;
      }
      hvec8 bfg[4];
#pragma unroll
      for (int nt = 0; nt < 4; ++nt)
        bfg[nt] = *(const hvec8*)(kvwh + (size_t)(n0w + nt * 16 + l15) * 256 + k0);
#pragma unroll
      for (int mt = 0; mt < 4; ++mt)
#pragma unroll
        for (int nt = 0; nt < 4; ++nt)
          acc[mt][nt] = __builtin_amdgcn_mfma_f32_16x16x32_f16(af[mt], bfg[nt], acc[mt][nt], 0, 0, 0);
    }
    // epilogue: + kv_b, write K natural / V transposed to LDS (f16)
#pragma unroll
    for (int nt = 0; nt < 4; ++nt) {
      const int n = n0w + nt * 16 + l15;     // kv channel (D col)
      const float bias = kvb[n];
      if (wv < 4) {
#pragma unroll
        for (int mt = 0; mt < 4; ++mt)
#pragma unroll
          for (int r = 0; r < 4; ++r) {
            int m = mt * 16 + l4 * 4 + r;    // window row (D row)
            Ks[m * 264 + n] = (_Float16)(acc[mt][nt][r] + bias);
          }
      } else {
        const int vn = n - 256;              // v channel 0..255
#pragma unroll
        for (int mt = 0; mt < 4; ++mt)
#pragma unroll
          for (int r = 0; r < 4; ++r) {
            int m = mt * 16 + l4 * 4 + r;
            Vt[vn * 68 + m] = (_Float16)(acc[mt][nt][r] + bias);
          }
      }
    }
  }
  __syncthreads();

  // ===== Preload K/V fragments for head h = wv (Ks/Vt die after this) ======
  const int h = wv;
  hvec8 kf[4];     // K B-frags: B[k=d][n=kk] = Ks[kk][h*32+d]
#pragma unroll
  for (int nt = 0; nt < 4; ++nt)
    kf[nt] = *(const hvec8*)&Ks[(nt * 16 + l15) * 264 + h * 32 + l4 * 8];
  H8 vf[2][2];     // V B-frags: B[k=kk][n=d] = Vt[h*32+d][kk]
#pragma unroll
  for (int nv = 0; nv < 2; ++nv)
#pragma unroll
    for (int k2 = 0; k2 < 2; ++k2) {
      int row = h * 32 + nv * 16 + l15;
      int kkb = k2 * 32 + l4 * 8;
      vf[nv][k2].v4[0] = *(const hvec4*)&Vt[row * 68 + kkb];
      vf[nv][k2].v4[1] = *(const hvec4*)&Vt[row * 68 + kkb + 4];
    }
  __syncthreads();   // all frags in regs; region may be reused as Os/Pc

  const float* bh = biasf + h * 4096;
  _Float16* pc = Pc + wv * (16 * 68);

  for (int half = 0; half < 2; ++half) {
    // =============== Stage B half: attention rows [half*64, half*64+64) =====
    {
      hvec8 qf[4];
#pragma unroll
      for (int q4 = 0; q4 < 4; ++q4) {
        int mt = half * 4 + q4;
        qf[q4] = *(const hvec8*)(qh + (size_t)(h * 128 + mt * 16 + l15) * 32 + l4 * 8);
      }
      for (int q4 = 0; q4 < 4; ++q4) {
        const int mt = half * 4 + q4;
        fvec4 s[4];
#pragma unroll
        for (int nt = 0; nt < 4; ++nt)
          s[nt] = __builtin_amdgcn_mfma_f32_16x16x32_f16(qf[q4], kf[nt], fz, 0, 0, 0);
        // + relative position bias (rows tile mod 64)
        const int pbase = (mt * 16 + l4 * 4) & 63;
#pragma unroll
        for (int r = 0; r < 4; ++r)
#pragma unroll
          for (int nt = 0; nt < 4; ++nt)
            s[nt][r] += bh[(pbase + r) * 64 + nt * 16 + l15];
        // in-register softmax over kk (4 in-lane regs x 16 lanes)
#pragma unroll
        for (int r = 0; r < 4; ++r) {
          float mx = fmaxf(fmaxf(s[0][r], s[1][r]), fmaxf(s[2][r], s[3][r]));
          mx = fmaxf(mx, __shfl_xor(mx, 1));
          mx = fmaxf(mx, __shfl_xor(mx, 2));
          mx = fmaxf(mx, __shfl_xor(mx, 4));
          mx = fmaxf(mx, __shfl_xor(mx, 8));
          float sm = 0.f;
#pragma unroll
          for (int nt = 0; nt < 4; ++nt) {
            float e = __expf(s[nt][r] - mx);
            s[nt][r] = e;
            sm += e;
          }
          sm += __shfl_xor(sm, 1);
          sm += __shfl_xor(sm, 2);
          sm += __shfl_xor(sm, 4);
          sm += __shfl_xor(sm, 8);
          const float iv = 1.0f / sm;
#pragma unroll
          for (int nt = 0; nt < 4; ++nt) s[nt][r] *= iv;
        }
        // P chunk -> LDS (wave-private; DS ops in-order within a wave)
#pragma unroll
        for (int nt = 0; nt < 4; ++nt)
#pragma unroll
          for (int r = 0; r < 4; ++r)
            pc[(l4 * 4 + r) * 68 + nt * 16 + l15] = (_Float16)s[nt][r];
        // P A-frags: A[m=q][k=kk]
        H8 pf[2];
#pragma unroll
        for (int k2 = 0; k2 < 2; ++k2) {
          int kkb = k2 * 32 + l4 * 8;
          pf[k2].v4[0] = *(const hvec4*)&pc[l15 * 68 + kkb];
          pf[k2].v4[1] = *(const hvec4*)&pc[l15 * 68 + kkb + 4];
        }
        fvec4 o[2];
#pragma unroll
        for (int nv = 0; nv < 2; ++nv) {
          o[nv] = __builtin_amdgcn_mfma_f32_16x16x32_f16(pf[0].v8, vf[nv][0].v8, fz, 0, 0, 0);
          o[nv] = __builtin_amdgcn_mfma_f32_16x16x32_f16(pf[1].v8, vf[nv][1].v8, o[nv], 0, 0, 0);
        }
#pragma unroll
        for (int nv = 0; nv < 2; ++nv)
#pragma unroll
          for (int r = 0; r < 4; ++r) {
            int row = q4 * 16 + l4 * 4 + r;          // local row in half
            int col = h * 32 + nv * 16 + l15;
            Os[row * 264 + col] = (_Float16)o[nv][r];
          }
      }
    }
    __syncthreads();

    // =============== Stage C half: out rows = Os[64][256] @ proj_w^T + b ====
    {
      const int c0 = wv * 32;  // out-channel slice per wave
      fvec4 po[4][2];
#pragma unroll
      for (int q4 = 0; q4 < 4; ++q4)
#pragma unroll
        for (int nb = 0; nb < 2; ++nb) po[q4][nb] = fz;

      for (int ks = 0; ks < 8; ++ks) {
        const int k0 = ks * 32 + l4 * 8;
        hvec8 am[4];
#pragma unroll
        for (int q4 = 0; q4 < 4; ++q4)
          am[q4] = *(const hvec8*)&Os[(q4 * 16 + l15) * 264 + k0];
        hvec8 bn[2];
#pragma unroll
        for (int nb = 0; nb < 2; ++nb)
          bn[nb] = *(const hvec8*)(pjwh + (size_t)(c0 + nb * 16 + l15) * 256 + k0);
#pragma unroll
        for (int q4 = 0; q4 < 4; ++q4)
#pragma unroll
          for (int nb = 0; nb < 2; ++nb)
            po[q4][nb] = __builtin_amdgcn_mfma_f32_16x16x32_f16(am[q4], bn[nb], po[q4][nb], 0, 0, 0);
      }
      float pb[2];
#pragma unroll
      for (int nb = 0; nb < 2; ++nb) pb[nb] = pjb[c0 + nb * 16 + l15];
      float* ow = out + (size_t)w * (N1 * DIM) + (size_t)half * 64 * DIM;
#pragma unroll
      for (int q4 = 0; q4 < 4; ++q4)
#pragma unroll
        for (int nb = 0; nb < 2; ++nb)
#pragma unroll
          for (int r = 0; r < 4; ++r) {
            int row = q4 * 16 + l4 * 4 + r;
            int col = c0 + nb * 16 + l15;
            ow[row * 256 + col] = po[q4][nb][r] + pb[nb];
          }
    }
    if (half == 0) __syncthreads();   // B2 rewrites Os after C1 reads
  }
}

// ---------------------------------------------------------------------------
extern "C" void kernel_launch(void* const* d_in, const int* in_sizes, int n_in,
                              void* d_out, int out_size, void* d_ws, size_t ws_size,
                              hipStream_t stream) {
  (void)in_sizes; (void)n_in; (void)out_size; (void)ws_size;
  const float* embeds = (const float*)d_in[0];  // [1,128,256]
  const float* x      = (const float*)d_in[1];  // [2,256,256,256]
  const float* rpb    = (const float*)d_in[2];  // [225,8]
  const float* kvw    = (const float*)d_in[3];  // [512,256]
  const float* kvb    = (const float*)d_in[4];  // [512]
  const float* pjw    = (const float*)d_in[5];  // [256,256]
  const float* pjb    = (const float*)d_in[6];  // [256]
  float* out = (float*)d_out;                   // [2048,128,256]

  char* ws = (char*)d_ws;                       // 576 KB used
  _Float16* qh    = (_Float16*)(ws);            // 65536 B  : q f16 [8][128][32]
  _Float16* kvwh  = (_Float16*)(ws + 65536);    // 262144 B : kv_w f16
  _Float16* pjwh  = (_Float16*)(ws + 327680);   // 131072 B : proj_w f16
  float*    biasf = (float*)(ws + 458752);      // 131072 B : bias fp32 [8][64][64]

  prep_kernel<<<512, 256, 0, stream>>>(embeds, rpb, kvw, pjw, qh, kvwh, pjwh, biasf);
  attn_kernel<<<NWIN, 512, 0, stream>>>(x, kvb, pjb, qh, kvwh, pjwh, biasf, out);
}